// Round 1
// baseline (228.619 us; speedup 1.0000x reference)
//
#include <hip/hip_runtime.h>
#include <hip/hip_bf16.h>
#include <math.h>

typedef _Float16 f16;
typedef _Float16 half8 __attribute__((ext_vector_type(8)));
typedef float f32x4 __attribute__((ext_vector_type(4)));

#define DIMC 512
#define HEADS 8
#define HD 64
#define BB 4
#define NN 2048
#define MM (BB*NN)        // 8192
#define NQKV (3*DIMC)     // 1536
#define SCALE 0.125f
#define EPSLN 1e-5f

// ---------------- LayerNorm + cast to fp16 ----------------
// one wave per row (512 elems, 8/lane)
__global__ __launch_bounds__(256) void ln_kernel(const float* __restrict__ x,
                                                 const float* __restrict__ gamma,
                                                 const float* __restrict__ beta,
                                                 f16* __restrict__ xn) {
    int w = threadIdx.x >> 6;
    int lane = threadIdx.x & 63;
    int row = blockIdx.x * 4 + w;
    const float* xr = x + (size_t)row * DIMC;
    float4 v0 = ((const float4*)xr)[lane * 2];
    float4 v1 = ((const float4*)xr)[lane * 2 + 1];
    float s = v0.x + v0.y + v0.z + v0.w + v1.x + v1.y + v1.z + v1.w;
#pragma unroll
    for (int off = 1; off < 64; off <<= 1) s += __shfl_xor(s, off);
    float mu = s * (1.0f / DIMC);
    float d0 = v0.x - mu, d1 = v0.y - mu, d2 = v0.z - mu, d3 = v0.w - mu;
    float d4 = v1.x - mu, d5 = v1.y - mu, d6 = v1.z - mu, d7 = v1.w - mu;
    float s2 = d0*d0 + d1*d1 + d2*d2 + d3*d3 + d4*d4 + d5*d5 + d6*d6 + d7*d7;
#pragma unroll
    for (int off = 1; off < 64; off <<= 1) s2 += __shfl_xor(s2, off);
    float rstd = rsqrtf(s2 * (1.0f / DIMC) + EPSLN);
    float4 g0 = ((const float4*)gamma)[lane * 2];
    float4 g1 = ((const float4*)gamma)[lane * 2 + 1];
    float4 b0 = ((const float4*)beta)[lane * 2];
    float4 b1 = ((const float4*)beta)[lane * 2 + 1];
    half8 o;
    o[0] = (f16)(d0 * rstd * g0.x + b0.x);
    o[1] = (f16)(d1 * rstd * g0.y + b0.y);
    o[2] = (f16)(d2 * rstd * g0.z + b0.z);
    o[3] = (f16)(d3 * rstd * g0.w + b0.w);
    o[4] = (f16)(d4 * rstd * g1.x + b1.x);
    o[5] = (f16)(d5 * rstd * g1.y + b1.y);
    o[6] = (f16)(d6 * rstd * g1.z + b1.z);
    o[7] = (f16)(d7 * rstd * g1.w + b1.w);
    ((half8*)(xn + (size_t)row * DIMC))[lane] = o;
}

// ---------------- cast + transpose weights ----------------
// wqkvt[n][k] = wqkv[k][n] (n<1536, k<512); wprojt[n][k] = wproj[k][n]
__global__ __launch_bounds__(256) void castw_kernel(const float* __restrict__ wqkv,
                                                    const float* __restrict__ wproj,
                                                    f16* __restrict__ wqkvt,
                                                    f16* __restrict__ wprojt) {
    int idx = blockIdx.x * 256 + threadIdx.x;
    if (idx < NQKV * DIMC) {
        int n = idx >> 9, k = idx & 511;
        wqkvt[idx] = (f16)wqkv[(size_t)k * NQKV + n];
    } else {
        int idx2 = idx - NQKV * DIMC;
        int n = idx2 >> 9, k = idx2 & 511;
        wprojt[idx2] = (f16)wproj[(size_t)k * DIMC + n];
    }
}

// ---------------- QKV GEMM: [8192,512] x [512,1536] ----------------
// block tile 64x64, 4 waves (2x2), each 32x32 via 2x2 mfma 16x16x32
// epilogue scatters q,k -> [B,H,N,D], v -> [B,H,D,N] (transposed), fp16
__global__ __launch_bounds__(256) void gemm_qkv(const f16* __restrict__ xn,
                                                const f16* __restrict__ wt,
                                                f16* __restrict__ qb,
                                                f16* __restrict__ kbuf,
                                                f16* __restrict__ vtb) {
    __shared__ __align__(16) f16 As[64 * 40];
    __shared__ __align__(16) f16 Bs[64 * 40];
    int tid = threadIdx.x;
    int m0 = blockIdx.y * 64;
    int c0 = blockIdx.x * 64;
    int w = tid >> 6, lane = tid & 63, l15 = lane & 15, quad = lane >> 4;
    int wy = w >> 1, wx = w & 1;
    f32x4 acc[2][2] = {};
    int srow = tid >> 2, skoff = (tid & 3) * 8;
    const f16* ag = xn + (size_t)(m0 + srow) * DIMC + skoff;
    const f16* bg = wt + (size_t)(c0 + srow) * DIMC + skoff;
    for (int kk = 0; kk < DIMC / 32; ++kk) {
        *(half8*)&As[srow * 40 + skoff] = *(const half8*)(ag + kk * 32);
        *(half8*)&Bs[srow * 40 + skoff] = *(const half8*)(bg + kk * 32);
        __syncthreads();
        half8 a0 = *(const half8*)&As[(wy * 32 + l15) * 40 + quad * 8];
        half8 a1 = *(const half8*)&As[(wy * 32 + 16 + l15) * 40 + quad * 8];
        half8 b0 = *(const half8*)&Bs[(wx * 32 + l15) * 40 + quad * 8];
        half8 b1 = *(const half8*)&Bs[(wx * 32 + 16 + l15) * 40 + quad * 8];
        acc[0][0] = __builtin_amdgcn_mfma_f32_16x16x32_f16(a0, b0, acc[0][0], 0, 0, 0);
        acc[0][1] = __builtin_amdgcn_mfma_f32_16x16x32_f16(a0, b1, acc[0][1], 0, 0, 0);
        acc[1][0] = __builtin_amdgcn_mfma_f32_16x16x32_f16(a1, b0, acc[1][0], 0, 0, 0);
        acc[1][1] = __builtin_amdgcn_mfma_f32_16x16x32_f16(a1, b1, acc[1][1], 0, 0, 0);
        __syncthreads();
    }
#pragma unroll
    for (int ti = 0; ti < 2; ti++)
#pragma unroll
        for (int tj = 0; tj < 2; tj++)
#pragma unroll
            for (int r = 0; r < 4; r++) {
                int m = m0 + wy * 32 + ti * 16 + quad * 4 + r;
                int c = c0 + wx * 32 + tj * 16 + l15;
                f16 bv = (f16)acc[ti][tj][r];
                int b = m >> 11, n = m & 2047;
                if (c < DIMC) {
                    int h = c >> 6, d = c & 63;
                    qb[(((size_t)(b * HEADS + h)) * NN + n) * HD + d] = bv;
                } else if (c < 2 * DIMC) {
                    int c2 = c - DIMC;
                    int h = c2 >> 6, d = c2 & 63;
                    kbuf[(((size_t)(b * HEADS + h)) * NN + n) * HD + d] = bv;
                } else {
                    int c2 = c - 2 * DIMC;
                    int h = c2 >> 6, d = c2 & 63;
                    vtb[(((size_t)(b * HEADS + h)) * HD + d) * NN + n] = bv;
                }
            }
}

// ---------------- Flash attention ----------------
// grid (N/64, B*H); block 256 = 4 waves; wave handles 16 queries
// computes S^T = K*Q^T so softmax reduces over regs + shfl_xor(16,32)
__global__ __launch_bounds__(256) void attn_kernel(const f16* __restrict__ qb,
                                                   const f16* __restrict__ kbuf,
                                                   const f16* __restrict__ vtb,
                                                   f16* __restrict__ ao) {
    __shared__ __align__(16) f16 Ks[64 * 72];
    __shared__ __align__(16) f16 Vs[64 * 72];
    __shared__ __align__(16) f16 Ps[4][16 * 72];
    int bh = blockIdx.y;
    int n0 = blockIdx.x * 64;
    int tid = threadIdx.x, w = tid >> 6, lane = tid & 63, l15 = lane & 15, quad = lane >> 4;
    const f16* Kbase = kbuf + (size_t)bh * NN * HD;
    const f16* Vbase = vtb + (size_t)bh * HD * NN;
    const f16* Qbase = qb + (size_t)bh * NN * HD;
    // preload Q fragments: wave's 16 queries, row = n0 + w*16 + l15
    half8 qf0, qf1;
    {
        const f16* qr = Qbase + (size_t)(n0 + w * 16 + l15) * HD + quad * 8;
        qf0 = *(const half8*)qr;
        qf1 = *(const half8*)(qr + 32);
    }
    f32x4 o[4] = {};
    float m_run = -INFINITY, l_run = 0.f;
    int srow = tid >> 2, sk = (tid & 3) * 8;
    for (int kt0 = 0; kt0 < NN; kt0 += 64) {
        // stage K tile [64 keys][64 d] and Vt tile [64 d][64 keys]
        {
            const f16* kg = Kbase + (size_t)(kt0 + srow) * HD + sk;
            *(half8*)&Ks[srow * 72 + sk] = *(const half8*)kg;
            *(half8*)&Ks[srow * 72 + sk + 32] = *(const half8*)(kg + 32);
            const f16* vg = Vbase + (size_t)srow * NN + kt0 + sk;
            *(half8*)&Vs[srow * 72 + sk] = *(const half8*)vg;
            *(half8*)&Vs[srow * 72 + sk + 32] = *(const half8*)(vg + 32);
        }
        __syncthreads();
        // S^T tiles: 4 x (16 keys x 16 queries)
        f32x4 s[4];
#pragma unroll
        for (int kt = 0; kt < 4; kt++) {
            f32x4 z = {};
            half8 a0 = *(const half8*)&Ks[(kt * 16 + l15) * 72 + quad * 8];
            half8 a1 = *(const half8*)&Ks[(kt * 16 + l15) * 72 + 32 + quad * 8];
            z = __builtin_amdgcn_mfma_f32_16x16x32_f16(a0, qf0, z, 0, 0, 0);
            z = __builtin_amdgcn_mfma_f32_16x16x32_f16(a1, qf1, z, 0, 0, 0);
            s[kt] = z;
        }
        float tmax = -INFINITY;
#pragma unroll
        for (int kt = 0; kt < 4; kt++)
#pragma unroll
            for (int r = 0; r < 4; r++) {
                s[kt][r] *= SCALE;
                tmax = fmaxf(tmax, s[kt][r]);
            }
        tmax = fmaxf(tmax, __shfl_xor(tmax, 16));
        tmax = fmaxf(tmax, __shfl_xor(tmax, 32));
        float m_new = fmaxf(m_run, tmax);
        float alpha = __expf(m_run - m_new);
        float lsum = 0.f;
#pragma unroll
        for (int kt = 0; kt < 4; kt++)
#pragma unroll
            for (int r = 0; r < 4; r++) {
                float p = __expf(s[kt][r] - m_new);
                s[kt][r] = p;
                lsum += p;
            }
        lsum += __shfl_xor(lsum, 16);
        lsum += __shfl_xor(lsum, 32);
        l_run = l_run * alpha + lsum;
        m_run = m_new;
        // rescale O rows (row q = quad*4+r; alpha indexed by l15 -> shuffle)
        float ar[4];
#pragma unroll
        for (int r = 0; r < 4; r++) ar[r] = __shfl(alpha, quad * 4 + r);
#pragma unroll
        for (int nt = 0; nt < 4; nt++)
#pragma unroll
            for (int r = 0; r < 4; r++) o[nt][r] *= ar[r];
        // P^T (C-layout) -> LDS in A-layout order P[q][key]
        f16* P = &Ps[w][0];
#pragma unroll
        for (int kt = 0; kt < 4; kt++)
#pragma unroll
            for (int r = 0; r < 4; r++)
                P[l15 * 72 + kt * 16 + quad * 4 + r] = (f16)s[kt][r];
        // PV: O[16q][64d] += P[16q][64k] * V[64k][64d]
        half8 pa0 = *(const half8*)&P[l15 * 72 + quad * 8];
        half8 pa1 = *(const half8*)&P[l15 * 72 + 32 + quad * 8];
#pragma unroll
        for (int nt = 0; nt < 4; nt++) {
            half8 vb0 = *(const half8*)&Vs[(nt * 16 + l15) * 72 + quad * 8];
            half8 vb1 = *(const half8*)&Vs[(nt * 16 + l15) * 72 + 32 + quad * 8];
            o[nt] = __builtin_amdgcn_mfma_f32_16x16x32_f16(pa0, vb0, o[nt], 0, 0, 0);
            o[nt] = __builtin_amdgcn_mfma_f32_16x16x32_f16(pa1, vb1, o[nt], 0, 0, 0);
        }
        __syncthreads();
    }
    // epilogue: divide by l, store [B][N][C] fp16 (C = h*64 + d)
    float lr[4];
#pragma unroll
    for (int r = 0; r < 4; r++) lr[r] = __shfl(l_run, quad * 4 + r);
    int h = bh & 7, b = bh >> 3;
#pragma unroll
    for (int nt = 0; nt < 4; nt++)
#pragma unroll
        for (int r = 0; r < 4; r++) {
            int n = n0 + w * 16 + quad * 4 + r;
            int c = h * 64 + nt * 16 + l15;
            ao[((size_t)(b * NN + n)) * DIMC + c] = (f16)(o[nt][r] / lr[r]);
        }
}

// ---------------- proj GEMM + bias + residual ----------------
__global__ __launch_bounds__(256) void gemm_proj(const f16* __restrict__ aob,
                                                 const f16* __restrict__ wt,
                                                 const float* __restrict__ x,
                                                 const float* __restrict__ bias,
                                                 float* __restrict__ out) {
    __shared__ __align__(16) f16 As[64 * 40];
    __shared__ __align__(16) f16 Bs[64 * 40];
    int tid = threadIdx.x;
    int m0 = blockIdx.y * 64;
    int c0 = blockIdx.x * 64;
    int w = tid >> 6, lane = tid & 63, l15 = lane & 15, quad = lane >> 4;
    int wy = w >> 1, wx = w & 1;
    f32x4 acc[2][2] = {};
    int srow = tid >> 2, skoff = (tid & 3) * 8;
    const f16* ag = aob + (size_t)(m0 + srow) * DIMC + skoff;
    const f16* bg = wt + (size_t)(c0 + srow) * DIMC + skoff;
    for (int kk = 0; kk < DIMC / 32; ++kk) {
        *(half8*)&As[srow * 40 + skoff] = *(const half8*)(ag + kk * 32);
        *(half8*)&Bs[srow * 40 + skoff] = *(const half8*)(bg + kk * 32);
        __syncthreads();
        half8 a0 = *(const half8*)&As[(wy * 32 + l15) * 40 + quad * 8];
        half8 a1 = *(const half8*)&As[(wy * 32 + 16 + l15) * 40 + quad * 8];
        half8 b0 = *(const half8*)&Bs[(wx * 32 + l15) * 40 + quad * 8];
        half8 b1 = *(const half8*)&Bs[(wx * 32 + 16 + l15) * 40 + quad * 8];
        acc[0][0] = __builtin_amdgcn_mfma_f32_16x16x32_f16(a0, b0, acc[0][0], 0, 0, 0);
        acc[0][1] = __builtin_amdgcn_mfma_f32_16x16x32_f16(a0, b1, acc[0][1], 0, 0, 0);
        acc[1][0] = __builtin_amdgcn_mfma_f32_16x16x32_f16(a1, b0, acc[1][0], 0, 0, 0);
        acc[1][1] = __builtin_amdgcn_mfma_f32_16x16x32_f16(a1, b1, acc[1][1], 0, 0, 0);
        __syncthreads();
    }
#pragma unroll
    for (int ti = 0; ti < 2; ti++)
#pragma unroll
        for (int tj = 0; tj < 2; tj++)
#pragma unroll
            for (int r = 0; r < 4; r++) {
                int m = m0 + wy * 32 + ti * 16 + quad * 4 + r;
                int c = c0 + wx * 32 + tj * 16 + l15;
                out[(size_t)m * DIMC + c] = x[(size_t)m * DIMC + c] + bias[c] + acc[ti][tj][r];
            }
}

extern "C" void kernel_launch(void* const* d_in, const int* in_sizes, int n_in,
                              void* d_out, int out_size, void* d_ws, size_t ws_size,
                              hipStream_t stream) {
    (void)in_sizes; (void)n_in; (void)out_size; (void)ws_size;
    const float* x     = (const float*)d_in[0];
    const float* wqkv  = (const float*)d_in[1];
    const float* wproj = (const float*)d_in[2];
    const float* bproj = (const float*)d_in[3];
    const float* gamma = (const float*)d_in[4];
    const float* beta  = (const float*)d_in[5];
    float* out = (float*)d_out;

    char* ws = (char*)d_ws;
    f16* xn     = (f16*)ws;                 ws += (size_t)MM * DIMC * 2;     // 8 MB
    f16* wqkvt  = (f16*)ws;                 ws += (size_t)NQKV * DIMC * 2;   // 1.5 MB
    f16* wprojt = (f16*)ws;                 ws += (size_t)DIMC * DIMC * 2;   // 0.5 MB
    f16* qbuf   = (f16*)ws;                 ws += (size_t)MM * DIMC * 2;     // 8 MB
    f16* kbuf   = (f16*)ws;                 ws += (size_t)MM * DIMC * 2;     // 8 MB
    f16* vtbuf  = (f16*)ws;                 ws += (size_t)MM * DIMC * 2;     // 8 MB
    f16* aobuf  = (f16*)ws;                 ws += (size_t)MM * DIMC * 2;     // 8 MB

    ln_kernel<<<MM / 4, 256, 0, stream>>>(x, gamma, beta, xn);
    castw_kernel<<<(NQKV * DIMC + DIMC * DIMC) / 256, 256, 0, stream>>>(wqkv, wproj, wqkvt, wprojt);
    gemm_qkv<<<dim3(NQKV / 64, MM / 64), 256, 0, stream>>>(xn, wqkvt, qbuf, kbuf, vtbuf);
    attn_kernel<<<dim3(NN / 64, BB * HEADS), 256, 0, stream>>>(qbuf, kbuf, vtbuf, aobuf);
    gemm_proj<<<dim3(DIMC / 64, MM / 64), 256, 0, stream>>>(aobuf, wprojt, x, bproj, out);
}

// Round 2
// 206.224 us; speedup vs baseline: 1.1086x; 1.1086x over previous
//
#include <hip/hip_runtime.h>
#include <hip/hip_bf16.h>
#include <math.h>

typedef _Float16 f16;
typedef _Float16 half8 __attribute__((ext_vector_type(8)));
typedef _Float16 half4 __attribute__((ext_vector_type(4)));
typedef float f32x4 __attribute__((ext_vector_type(4)));

#define DIMC 512
#define HEADS 8
#define HD 64
#define BB 4
#define NN 2048
#define MM (BB*NN)        // 8192
#define NQKV (3*DIMC)     // 1536
#define SCALE 0.125f
#define LOG2E 1.44269504f
#define EPSLN 1e-5f

__device__ __forceinline__ void g2l16(const void* g, void* l) {
    __builtin_amdgcn_global_load_lds(
        (const __attribute__((address_space(1))) unsigned int*)g,
        (__attribute__((address_space(3))) unsigned int*)l, 16, 0, 0);
}

// ---------------- LayerNorm + cast to fp16 ----------------
__global__ __launch_bounds__(256) void ln_kernel(const float* __restrict__ x,
                                                 const float* __restrict__ gamma,
                                                 const float* __restrict__ beta,
                                                 f16* __restrict__ xn) {
    int w = threadIdx.x >> 6;
    int lane = threadIdx.x & 63;
    int row = blockIdx.x * 4 + w;
    const float* xr = x + (size_t)row * DIMC;
    float4 v0 = ((const float4*)xr)[lane * 2];
    float4 v1 = ((const float4*)xr)[lane * 2 + 1];
    float s = v0.x + v0.y + v0.z + v0.w + v1.x + v1.y + v1.z + v1.w;
#pragma unroll
    for (int off = 1; off < 64; off <<= 1) s += __shfl_xor(s, off);
    float mu = s * (1.0f / DIMC);
    float d0 = v0.x - mu, d1 = v0.y - mu, d2 = v0.z - mu, d3 = v0.w - mu;
    float d4 = v1.x - mu, d5 = v1.y - mu, d6 = v1.z - mu, d7 = v1.w - mu;
    float s2 = d0*d0 + d1*d1 + d2*d2 + d3*d3 + d4*d4 + d5*d5 + d6*d6 + d7*d7;
#pragma unroll
    for (int off = 1; off < 64; off <<= 1) s2 += __shfl_xor(s2, off);
    float rstd = rsqrtf(s2 * (1.0f / DIMC) + EPSLN);
    float4 g0 = ((const float4*)gamma)[lane * 2];
    float4 g1 = ((const float4*)gamma)[lane * 2 + 1];
    float4 b0 = ((const float4*)beta)[lane * 2];
    float4 b1 = ((const float4*)beta)[lane * 2 + 1];
    half8 o;
    o[0] = (f16)(d0 * rstd * g0.x + b0.x);
    o[1] = (f16)(d1 * rstd * g0.y + b0.y);
    o[2] = (f16)(d2 * rstd * g0.z + b0.z);
    o[3] = (f16)(d3 * rstd * g0.w + b0.w);
    o[4] = (f16)(d4 * rstd * g1.x + b1.x);
    o[5] = (f16)(d5 * rstd * g1.y + b1.y);
    o[6] = (f16)(d6 * rstd * g1.z + b1.z);
    o[7] = (f16)(d7 * rstd * g1.w + b1.w);
    ((half8*)(xn + (size_t)row * DIMC))[lane] = o;
}

// ---------------- transpose + cast via LDS: dst[C][R] = src[R][C] ----------------
// tile: 32 rows(R) x 64 cols(C); grid (C/64, R/32)
__global__ __launch_bounds__(256) void transpose_cast(const float* __restrict__ src,
                                                      f16* __restrict__ dst,
                                                      int R, int C) {
    __shared__ f16 t[32][72];
    int k0 = blockIdx.y * 32, n0 = blockIdx.x * 64;
    int tid = threadIdx.x;
    int rr = tid >> 6, col = tid & 63;
#pragma unroll
    for (int p = 0; p < 8; p++) {
        int r = p * 4 + rr;
        t[r][col] = (f16)src[(size_t)(k0 + r) * C + n0 + col];
    }
    __syncthreads();
    int nl = tid >> 2, kc = (tid & 3) * 8;
    half8 v;
#pragma unroll
    for (int j = 0; j < 8; j++) v[j] = t[kc + j][nl];
    *(half8*)&dst[(size_t)(n0 + nl) * R + k0 + kc] = v;
}

// ---------------- shared 128x128 GEMM mainloop (BK=32, m97-style) ----------------
__device__ __forceinline__ void gemm128_loop(const char* Ag, const char* Bg,
                                             f16* As, f16* Bs, f32x4 (&acc)[4][4]) {
    int tid = threadIdx.x;
    int w = tid >> 6, lane = tid & 63, l15 = lane & 15, quad = lane >> 4;
    int wy = w >> 1, wx = w & 1;
    int off0 = w * 1024 + lane * 16;
    for (int kk = 0; kk < 16; ++kk) {
        __syncthreads();
#pragma unroll
        for (int c = 0; c < 2; ++c) {
            int off = c * 4096 + off0;
            int row = off >> 6, col = off & 63;
            g2l16(Ag + (size_t)row * 1024 + kk * 64 + col, (char*)As + c * 4096 + w * 1024);
            g2l16(Bg + (size_t)row * 1024 + kk * 64 + col, (char*)Bs + c * 4096 + w * 1024);
        }
        __syncthreads();
        half8 af[4], bf[4];
#pragma unroll
        for (int i = 0; i < 4; ++i) {
            af[i] = *(const half8*)((const char*)As + ((wy * 64 + i * 16 + l15) << 6) + quad * 16);
            bf[i] = *(const half8*)((const char*)Bs + ((wx * 64 + i * 16 + l15) << 6) + quad * 16);
        }
#pragma unroll
        for (int i = 0; i < 4; ++i)
#pragma unroll
            for (int j = 0; j < 4; ++j)
                acc[i][j] = __builtin_amdgcn_mfma_f32_16x16x32_f16(af[i], bf[j], acc[i][j], 0, 0, 0);
    }
}

// ---------------- QKV GEMM 128x128, scatter epilogue ----------------
__global__ __launch_bounds__(256) void gemm_qkv(const f16* __restrict__ xn,
                                                const f16* __restrict__ wt,
                                                f16* __restrict__ qb,
                                                f16* __restrict__ kbuf,
                                                f16* __restrict__ vtb) {
    __shared__ __align__(16) f16 As[128 * 32];
    __shared__ __align__(16) f16 Bs[128 * 32];
    int tid = threadIdx.x;
    int w = tid >> 6, lane = tid & 63, l15 = lane & 15, quad = lane >> 4;
    int wy = w >> 1, wx = w & 1;
    int m0 = blockIdx.y * 128, c0 = blockIdx.x * 128;
    f32x4 acc[4][4] = {};
    gemm128_loop((const char*)(xn + (size_t)m0 * DIMC),
                 (const char*)(wt + (size_t)c0 * DIMC), As, Bs, acc);
    const float QS = SCALE * LOG2E;   // folded into Q for exp2-domain softmax
#pragma unroll
    for (int i = 0; i < 4; ++i)
#pragma unroll
        for (int j = 0; j < 4; ++j)
#pragma unroll
            for (int r = 0; r < 4; ++r) {
                int m = m0 + wy * 64 + i * 16 + quad * 4 + r;
                int c = c0 + wx * 64 + j * 16 + l15;
                int b = m >> 11, n = m & 2047;
                float v = acc[i][j][r];
                if (c < DIMC) {
                    int h = c >> 6, d = c & 63;
                    qb[(((size_t)(b * HEADS + h)) * NN + n) * HD + d] = (f16)(v * QS);
                } else if (c < 2 * DIMC) {
                    int c2 = c - DIMC;
                    int h = c2 >> 6, d = c2 & 63;
                    kbuf[(((size_t)(b * HEADS + h)) * NN + n) * HD + d] = (f16)v;
                } else {
                    int c2 = c - 2 * DIMC;
                    int h = c2 >> 6, d = c2 & 63;
                    vtb[(((size_t)(b * HEADS + h)) * HD + d) * NN + n] = (f16)v;
                }
            }
}

// ---------------- proj GEMM 128x128 + bias + residual ----------------
__global__ __launch_bounds__(256) void gemm_proj(const f16* __restrict__ aob,
                                                 const f16* __restrict__ wt,
                                                 const float* __restrict__ x,
                                                 const float* __restrict__ bias,
                                                 float* __restrict__ out) {
    __shared__ __align__(16) f16 As[128 * 32];
    __shared__ __align__(16) f16 Bs[128 * 32];
    int tid = threadIdx.x;
    int w = tid >> 6, lane = tid & 63, l15 = lane & 15, quad = lane >> 4;
    int wy = w >> 1, wx = w & 1;
    int m0 = blockIdx.y * 128, c0 = blockIdx.x * 128;
    f32x4 acc[4][4] = {};
    gemm128_loop((const char*)(aob + (size_t)m0 * DIMC),
                 (const char*)(wt + (size_t)c0 * DIMC), As, Bs, acc);
#pragma unroll
    for (int i = 0; i < 4; ++i)
#pragma unroll
        for (int j = 0; j < 4; ++j)
#pragma unroll
            for (int r = 0; r < 4; ++r) {
                int m = m0 + wy * 64 + i * 16 + quad * 4 + r;
                int c = c0 + wx * 64 + j * 16 + l15;
                out[(size_t)m * DIMC + c] = x[(size_t)m * DIMC + c] + bias[c] + acc[i][j][r];
            }
}

// ---------------- Flash attention: 128 queries/block, 32/wave ----------------
// Q pre-scaled by SCALE*log2(e); softmax in exp2 domain.
__global__ __launch_bounds__(256) void attn_kernel(const f16* __restrict__ qb,
                                                   const f16* __restrict__ kbuf,
                                                   const f16* __restrict__ vtb,
                                                   f16* __restrict__ ao) {
    __shared__ __align__(16) f16 Ks[64 * 72];
    __shared__ __align__(16) f16 Vs[64 * 72];
    __shared__ __align__(16) f16 Ps[4][32 * 72];
    int bh = blockIdx.y;
    int n0 = blockIdx.x * 128;
    int tid = threadIdx.x, w = tid >> 6, lane = tid & 63, l15 = lane & 15, quad = lane >> 4;
    const f16* Kbase = kbuf + (size_t)bh * NN * HD;
    const f16* Vbase = vtb + (size_t)bh * HD * NN;
    const f16* Qbase = qb + (size_t)bh * NN * HD;
    half8 qf[2][2];
#pragma unroll
    for (int qt = 0; qt < 2; ++qt) {
        const f16* qr = Qbase + (size_t)(n0 + w * 32 + qt * 16 + l15) * HD + quad * 8;
        qf[qt][0] = *(const half8*)qr;
        qf[qt][1] = *(const half8*)(qr + 32);
    }
    f32x4 o[2][4] = {};
    float m_run[2] = {-INFINITY, -INFINITY};
    float l_run[2] = {0.f, 0.f};
    int srow = tid >> 2, part = tid & 3;
    for (int kt0 = 0; kt0 < NN; kt0 += 64) {
        __syncthreads();
        {
            const f16* kg = Kbase + (size_t)(kt0 + srow) * HD + part * 16;
            *(half8*)&Ks[srow * 72 + part * 16] = *(const half8*)kg;
            *(half8*)&Ks[srow * 72 + part * 16 + 8] = *(const half8*)(kg + 8);
            const f16* vg = Vbase + (size_t)srow * NN + kt0 + part * 16;
            *(half8*)&Vs[srow * 72 + part * 16] = *(const half8*)vg;
            *(half8*)&Vs[srow * 72 + part * 16 + 8] = *(const half8*)(vg + 8);
        }
        __syncthreads();
        half8 kf[4][2];
#pragma unroll
        for (int kt = 0; kt < 4; ++kt) {
            kf[kt][0] = *(const half8*)&Ks[(kt * 16 + l15) * 72 + quad * 8];
            kf[kt][1] = *(const half8*)&Ks[(kt * 16 + l15) * 72 + 32 + quad * 8];
        }
#pragma unroll
        for (int qt = 0; qt < 2; ++qt) {
            f32x4 s[4];
#pragma unroll
            for (int kt = 0; kt < 4; ++kt) {
                f32x4 z = {};
                z = __builtin_amdgcn_mfma_f32_16x16x32_f16(kf[kt][0], qf[qt][0], z, 0, 0, 0);
                z = __builtin_amdgcn_mfma_f32_16x16x32_f16(kf[kt][1], qf[qt][1], z, 0, 0, 0);
                s[kt] = z;
            }
            float tmax = -INFINITY;
#pragma unroll
            for (int kt = 0; kt < 4; ++kt)
#pragma unroll
                for (int r = 0; r < 4; ++r) tmax = fmaxf(tmax, s[kt][r]);
            tmax = fmaxf(tmax, __shfl_xor(tmax, 16));
            tmax = fmaxf(tmax, __shfl_xor(tmax, 32));
            float m_new = fmaxf(m_run[qt], tmax);
            float alpha = __builtin_amdgcn_exp2f(m_run[qt] - m_new);
            float lsum = 0.f;
#pragma unroll
            for (int kt = 0; kt < 4; ++kt)
#pragma unroll
                for (int r = 0; r < 4; ++r) {
                    float p = __builtin_amdgcn_exp2f(s[kt][r] - m_new);
                    s[kt][r] = p;
                    lsum += p;
                }
            lsum += __shfl_xor(lsum, 16);
            lsum += __shfl_xor(lsum, 32);
            l_run[qt] = l_run[qt] * alpha + lsum;
            m_run[qt] = m_new;
            float ar[4];
#pragma unroll
            for (int r = 0; r < 4; ++r) ar[r] = __shfl(alpha, quad * 4 + r);
#pragma unroll
            for (int nt = 0; nt < 4; ++nt)
#pragma unroll
                for (int r = 0; r < 4; ++r) o[qt][nt][r] *= ar[r];
            f16* P = &Ps[w][0] + (qt * 16 + l15) * 72;
#pragma unroll
            for (int kt = 0; kt < 4; ++kt) {
                half4 pk;
#pragma unroll
                for (int r = 0; r < 4; ++r) pk[r] = (f16)s[kt][r];
                *(half4*)&P[kt * 16 + quad * 4] = pk;
            }
        }
        // PV: O[32q][64d] += P[32q][64k] * V[64k][64d]
#pragma unroll
        for (int qt = 0; qt < 2; ++qt) {
            half8 pa0 = *(const half8*)&Ps[w][(qt * 16 + l15) * 72 + quad * 8];
            half8 pa1 = *(const half8*)&Ps[w][(qt * 16 + l15) * 72 + 32 + quad * 8];
#pragma unroll
            for (int nt = 0; nt < 4; ++nt) {
                half8 vb0 = *(const half8*)&Vs[(nt * 16 + l15) * 72 + quad * 8];
                half8 vb1 = *(const half8*)&Vs[(nt * 16 + l15) * 72 + 32 + quad * 8];
                o[qt][nt] = __builtin_amdgcn_mfma_f32_16x16x32_f16(pa0, vb0, o[qt][nt], 0, 0, 0);
                o[qt][nt] = __builtin_amdgcn_mfma_f32_16x16x32_f16(pa1, vb1, o[qt][nt], 0, 0, 0);
            }
        }
    }
    int h = bh & 7, b = bh >> 3;
#pragma unroll
    for (int qt = 0; qt < 2; ++qt) {
        float lr[4];
#pragma unroll
        for (int r = 0; r < 4; ++r) lr[r] = __shfl(l_run[qt], quad * 4 + r);
#pragma unroll
        for (int nt = 0; nt < 4; ++nt)
#pragma unroll
            for (int r = 0; r < 4; ++r) {
                int n = n0 + w * 32 + qt * 16 + quad * 4 + r;
                int c = h * 64 + nt * 16 + l15;
                ao[((size_t)(b * NN + n)) * DIMC + c] = (f16)(o[qt][nt][r] / lr[r]);
            }
    }
}

extern "C" void kernel_launch(void* const* d_in, const int* in_sizes, int n_in,
                              void* d_out, int out_size, void* d_ws, size_t ws_size,
                              hipStream_t stream) {
    (void)in_sizes; (void)n_in; (void)out_size; (void)ws_size;
    const float* x     = (const float*)d_in[0];
    const float* wqkv  = (const float*)d_in[1];
    const float* wproj = (const float*)d_in[2];
    const float* bproj = (const float*)d_in[3];
    const float* gamma = (const float*)d_in[4];
    const float* beta  = (const float*)d_in[5];
    float* out = (float*)d_out;

    char* ws = (char*)d_ws;
    f16* xn     = (f16*)ws;                 ws += (size_t)MM * DIMC * 2;
    f16* wqkvt  = (f16*)ws;                 ws += (size_t)NQKV * DIMC * 2;
    f16* wprojt = (f16*)ws;                 ws += (size_t)DIMC * DIMC * 2;
    f16* qbuf   = (f16*)ws;                 ws += (size_t)MM * DIMC * 2;
    f16* kbuf   = (f16*)ws;                 ws += (size_t)MM * DIMC * 2;
    f16* vtbuf  = (f16*)ws;                 ws += (size_t)MM * DIMC * 2;
    f16* aobuf  = (f16*)ws;                 ws += (size_t)MM * DIMC * 2;

    ln_kernel<<<MM / 4, 256, 0, stream>>>(x, gamma, beta, xn);
    transpose_cast<<<dim3(NQKV / 64, DIMC / 32), 256, 0, stream>>>(wqkv, wqkvt, DIMC, NQKV);
    transpose_cast<<<dim3(DIMC / 64, DIMC / 32), 256, 0, stream>>>(wproj, wprojt, DIMC, DIMC);
    gemm_qkv<<<dim3(NQKV / 128, MM / 128), 256, 0, stream>>>(xn, wqkvt, qbuf, kbuf, vtbuf);
    attn_kernel<<<dim3(NN / 128, BB * HEADS), 256, 0, stream>>>(qbuf, kbuf, vtbuf, aobuf);
    gemm_proj<<<dim3(DIMC / 128, MM / 128), 256, 0, stream>>>(aobuf, wprojt, x, bproj, out);
}